// Round 8
// baseline (254.621 us; speedup 1.0000x reference)
//
#include <hip/hip_runtime.h>
#include <stdint.h>

#define NCLS 80
#define BATCH 8
#define NA 20460          // total anchors per image across 5 levels
#define TOPK 1000
#define MAXPER 100
#define POOL 256          // merge candidate pool (top-100 + tie slack)
#define IMG_WF 1280.0f
#define IMG_HF 768.0f
#define CLS_OFF 4096.0f
#define MAX_RATIO_ANCHOR 13.815510557964274f  // |log(1e-6)|
#define MAX_RATIO_BBOX   4.1351665567423557f  // |log(16/1000)|

// RN(a/b) > 0.5  <=>  a > b*(0.5 + 2^-25) as reals (0.5 mantissa even, tie->down).
// b has 24-bit mantissa, K2 has 25 -> product exact in f64; comparison exact.
#define K2_HALF_UP (0.5 + 0x1p-25)

__constant__ int   c_lvoff[6]  = {0, 15360, 19200, 20160, 20400, 20460};
__constant__ int   c_lvoff4[6] = {0, 3840, 4800, 5040, 5100, 5115};   // /4
__constant__ int   c_lw[5]    = {160, 80, 40, 20, 10};
__constant__ int   c_lh[5]    = {96, 48, 24, 12, 6};
__constant__ float c_ls[5]    = {8.f, 16.f, 32.f, 64.f, 128.f};

struct InPtrs {
  const float* cls[5];
  const float* bbox[5];
  const float* shp[5];
  const float* loc[5];
};

__device__ __forceinline__ float sigf(float x) { return 1.0f / (1.0f + expf(-x)); }

// ---- DPP wave64 reductions (VALU-only) ----
#define DPP_STEP_U(op, ctrl, old) \
  t = (unsigned)__builtin_amdgcn_update_dpp((int)(old), (int)v, ctrl, 0xf, 0xf, false); \
  v = op(v, t);

__device__ __forceinline__ unsigned wave_red_max_u32(unsigned v) {
  unsigned t;
  DPP_STEP_U(max, 0x111, 0u) DPP_STEP_U(max, 0x112, 0u) DPP_STEP_U(max, 0x114, 0u)
  DPP_STEP_U(max, 0x118, 0u) DPP_STEP_U(max, 0x142, 0u) DPP_STEP_U(max, 0x143, 0u)
  return (unsigned)__builtin_amdgcn_readlane((int)v, 63);
}
__device__ __forceinline__ int wave_red_sum_i32(int v) {
  int t;
  t = __builtin_amdgcn_update_dpp(0, v, 0x111, 0xf, 0xf, false); v += t;
  t = __builtin_amdgcn_update_dpp(0, v, 0x112, 0xf, 0xf, false); v += t;
  t = __builtin_amdgcn_update_dpp(0, v, 0x114, 0xf, 0xf, false); v += t;
  t = __builtin_amdgcn_update_dpp(0, v, 0x118, 0xf, 0xf, false); v += t;
  t = __builtin_amdgcn_update_dpp(0, v, 0x142, 0xf, 0xf, false); v += t;
  t = __builtin_amdgcn_update_dpp(0, v, 0x143, 0xf, 0xf, false); v += t;
  return __builtin_amdgcn_readlane(v, 63);
}
// top-2 of the wave's values: merge op over disjoint sets is exact; the
// row_shr/bcast tree's lane-63 dependency path covers each lane exactly once.
__device__ __forceinline__ void wave_red_top2(unsigned m1, unsigned m2,
                                              unsigned& r1, unsigned& r2) {
#define T2STEP(ctrl) { \
    unsigned o1 = (unsigned)__builtin_amdgcn_update_dpp(0, (int)m1, ctrl, 0xf, 0xf, false); \
    unsigned o2 = (unsigned)__builtin_amdgcn_update_dpp(0, (int)m2, ctrl, 0xf, 0xf, false); \
    unsigned tm = min(m1, o1); \
    m1 = max(m1, o1); \
    m2 = max(tm, max(m2, o2)); }
  T2STEP(0x111) T2STEP(0x112) T2STEP(0x114) T2STEP(0x118) T2STEP(0x142) T2STEP(0x143)
#undef T2STEP
  r1 = (unsigned)__builtin_amdgcn_readlane((int)m1, 63);
  r2 = (unsigned)__builtin_amdgcn_readlane((int)m2, 63);
}

// ---------------- K1: per-anchor max score, float4 over 4 anchors/thread --------
__global__ __launch_bounds__(256) void k_maxscore(InPtrs P, float* maxscore) {
  int gid = blockIdx.x * 256 + threadIdx.x;
  if (gid >= BATCH * (NA / 4)) return;
  int b = gid / (NA / 4);
  int q = gid - b * (NA / 4);          // float4 index within batch (level-merged)
  int l = 0;
  while (q >= c_lvoff4[l + 1]) ++l;
  int hw = c_lh[l] * c_lw[l];
  int sp = (q - c_lvoff4[l]) * 4;
  const float4* cls = (const float4*)(P.cls[l] + (size_t)(b * NCLS) * hw + sp);
  int s4 = hw >> 2;                    // class stride in float4 units
  float4 m = cls[0];
  for (int c = 1; c < NCLS; ++c) {
    float4 v = cls[(size_t)c * s4];
    m.x = fmaxf(m.x, v.x); m.y = fmaxf(m.y, v.y);
    m.z = fmaxf(m.z, v.z); m.w = fmaxf(m.w, v.w);
  }
  float4 lo = *(const float4*)(P.loc[l] + (size_t)b * hw + sp);
  float4 r;
  r.x = (sigf(lo.x) >= 0.01f) ? sigf(sigf(m.x)) : 0.0f;  // monotone: max commutes
  r.y = (sigf(lo.y) >= 0.01f) ? sigf(sigf(m.y)) : 0.0f;
  r.z = (sigf(lo.z) >= 0.01f) ? sigf(sigf(m.z)) : 0.0f;
  r.w = (sigf(lo.w) >= 0.01f) ? sigf(sigf(m.w)) : 0.0f;
  ((float4*)maxscore)[(size_t)b * (NA / 4) + q] = r;
}

// ---------------- K2: exact top-1000 per batch, in top_k order ----------------
__global__ __launch_bounds__(1024) void k_select(const float* maxscore, int* sel) {
  int b = blockIdx.x;
  const unsigned int* ms = (const unsigned int*)(maxscore + (size_t)b * NA);
  int tid = threadIdx.x;
  int wv = tid >> 6;
  int lane = tid & 63;
  __shared__ int s_part[2][16];       // parity double-buffered partials
  __shared__ int s_pos;
  __shared__ int s_wtot[16];
  __shared__ unsigned long long s_keys[1024];

  unsigned v[20];
  #pragma unroll
  for (int k = 0; k < 20; ++k) {
    int i = tid + k * 1024;
    v[k] = (i < NA) ? ms[i] : 0u;
  }

  int par = 0;
  auto countGE = [&](unsigned mid) -> int {
    int c = 0;
    #pragma unroll
    for (int k = 0; k < 20; ++k) c += (v[k] >= mid) ? 1 : 0;
    c = wave_red_sum_i32(c);
    if (lane == 0) s_part[par][wv] = c;
    __syncthreads();
    int tot = 0;
    #pragma unroll
    for (int w = 0; w < 16; ++w) tot += s_part[par][w];
    par ^= 1;
    return tot;
  };

  // any nonzero score = sig(sig(x)) > 0.5 (bits >= 0x3F000001) and < 0.734375
  unsigned lo, hi;
  if (countGE(0x3F000001u) >= TOPK) { lo = 0x3F000001u; hi = 0x3F3C0000u; }
  else                              { lo = 0u;          hi = 1u; }       // V = 0
  while (hi - lo > 1u) {
    unsigned mid = lo + (hi - lo) / 2u;
    if (countGE(mid) >= TOPK) lo = mid; else hi = mid;
  }
  unsigned V = lo;  // bit pattern of the 1000th-largest value

  if (tid == 0) s_pos = 0;
  if (tid < 1024 - TOPK) s_keys[TOPK + tid] = 0ull;  // pads sink to the end
  __syncthreads();
  #pragma unroll
  for (int k = 0; k < 20; ++k) {
    int i = tid + k * 1024;
    if (v[k] > V) {   // count(>V) < 1000 guaranteed
      int p = atomicAdd(&s_pos, 1);
      s_keys[p] = ((unsigned long long)v[k] << 32) |
                  (unsigned long long)(0xFFFFFFFFu - (unsigned)i);
    }
  }
  __syncthreads();
  int ngt = s_pos;
  int need = TOPK - ngt;  // >= 1; filled by ==V in ascending index order
  const int CH = (NA + 1023) / 1024;  // 20, contiguous chunks (L2-hot re-read)
  int i0 = tid * CH, i1 = min(i0 + CH, NA);
  int ceq = 0;
  for (int i = i0; i < i1; ++i) ceq += (ms[i] == V) ? 1 : 0;

  // exclusive prefix over 1024 threads: shfl intra-wave scan + wave offsets
  int incl = ceq;
  #pragma unroll
  for (int o = 1; o < 64; o <<= 1) {
    int u = __shfl_up(incl, o, 64);
    if (lane >= o) incl += u;
  }
  if (lane == 63) s_wtot[wv] = incl;   // wave total
  __syncthreads();
  int woff = 0;
  #pragma unroll
  for (int w = 0; w < 16; ++w) woff += (w < wv) ? s_wtot[w] : 0;
  int r = woff + incl - ceq;           // global exclusive prefix
  for (int i = i0; i < i1 && r < need; ++i) {
    if (ms[i] == V) {
      s_keys[ngt + r] = ((unsigned long long)V << 32) |
                        (unsigned long long)(0xFFFFFFFFu - (unsigned)i);
      ++r;
    }
  }
  __syncthreads();

  // bitonic sort 1024 keys, descending (score desc, then anchor index asc)
  for (unsigned int k = 2; k <= 1024; k <<= 1) {
    for (unsigned int j = k >> 1; j > 0; j >>= 1) {
      unsigned int i = (unsigned int)tid;
      unsigned int l = i ^ j;
      if (l > i) {
        unsigned long long a = s_keys[i], bk = s_keys[l];
        bool swap = ((i & k) == 0) ? (a < bk) : (a > bk);
        if (swap) { s_keys[i] = bk; s_keys[l] = a; }
      }
      __syncthreads();
    }
  }
  if (tid < TOPK) {
    sel[b * TOPK + tid] = (int)(0xFFFFFFFFu - (unsigned)(s_keys[tid] & 0xFFFFFFFFull));
  }
}

// ---------------- K3: decode boxes + 80 class scores, one WAVE per row ----------
// sv is ROW-MAJOR [b][row][class]: the 80 scores per row are written contiguously
// (coalesced); k_nms's one-time strided read is L2-resident.
__global__ __launch_bounds__(256) void k_gather(InPtrs P, const int* sel, float* boxes, float* sv) {
  int wid = blockIdx.x * 4 + (threadIdx.x >> 6);
  int lane = threadIdx.x & 63;
  if (wid >= BATCH * TOPK) return;
  int b = wid / TOPK;
  int r = wid - b * TOPK;
  int a = sel[b * TOPK + r];       // uniform -> broadcast load
  int l = 0;
  while (a >= c_lvoff[l + 1]) ++l;
  int within = a - c_lvoff[l];
  int W = c_lw[l], H = c_lh[l];
  int y = within / W, x = within - y * W;
  int hw = H * W;
  int sp = within;
  float stride = c_ls[l];
  float px = (float)x * stride;
  float py = (float)y * stride;
  float pw = 4.0f * stride;

  // guided anchor from shape_pred (delta2bbox, dx=dy=0, no clip) — wave-uniform
  const float* shp = P.shp[l];
  float dws = shp[(b * 2 + 0) * hw + sp];
  float dhs = shp[(b * 2 + 1) * hw + sp];
  dws = fminf(fmaxf(dws, -MAX_RATIO_ANCHOR), MAX_RATIO_ANCHOR);
  dhs = fminf(fmaxf(dhs, -MAX_RATIO_ANCHOR), MAX_RATIO_ANCHOR);
  float gw = pw * expf(dws);
  float gh = pw * expf(dhs);
  float ax1 = px - 0.5f * gw, ax2 = px + 0.5f * gw;
  float ay1 = py - 0.5f * gh, ay2 = py + 0.5f * gh;

  // proposal from bbox_pred (delta2bbox with image clip)
  const float* bb = P.bbox[l];
  float dx = bb[(b * 4 + 0) * hw + sp];
  float dy = bb[(b * 4 + 1) * hw + sp];
  float dw = bb[(b * 4 + 2) * hw + sp];
  float dh = bb[(b * 4 + 3) * hw + sp];
  dw = fminf(fmaxf(dw, -MAX_RATIO_BBOX), MAX_RATIO_BBOX);
  dh = fminf(fmaxf(dh, -MAX_RATIO_BBOX), MAX_RATIO_BBOX);
  float px2 = (ax1 + ax2) * 0.5f, py2 = (ay1 + ay2) * 0.5f;
  float pw2 = ax2 - ax1, ph2 = ay2 - ay1;
  float gx = px2 + pw2 * dx, gy = py2 + ph2 * dy;
  float gw2 = pw2 * expf(dw), gh2 = ph2 * expf(dh);
  float x1 = fminf(fmaxf(gx - 0.5f * gw2, 0.0f), IMG_WF);
  float x2 = fminf(fmaxf(gx + 0.5f * gw2, 0.0f), IMG_WF);
  float y1 = fminf(fmaxf(gy - 0.5f * gh2, 0.0f), IMG_HF);
  float y2 = fminf(fmaxf(gy + 0.5f * gh2, 0.0f), IMG_HF);
  if (lane == 0) {
    float4 st; st.x = x1; st.y = y1; st.z = x2; st.w = y2;
    ((float4*)boxes)[b * TOPK + r] = st;
  }

  // scores: lane -> class (lanes handle c and c+64); contiguous per-row writes
  const float* cls = P.cls[l];
  float sl = sigf(P.loc[l][b * hw + sp]);
  bool mask = (sl >= 0.01f);
  int base = (b * NCLS) * hw + sp;
  float* svr = sv + (size_t)(b * TOPK + r) * NCLS;
  for (int c = lane; c < NCLS; c += 64) {
    float vv = 0.0f;
    if (mask) {
      float s2 = sigf(sigf(cls[base + c * hw]));
      vv = (s2 > 0.05f) ? s2 : 0.0f;   // SCORE_THR (strict >)
    }
    svr[c] = vv;
  }
}

// ---------------- K4: per-(batch,class) greedy NMS, FOUR waves, TWO picks/round --
// Packed u32 key: live scores sig(sig(x)) in (0.5, 0.734) share float bits[31:22]
// == 0x0FC, so key = (score_low22 << 10) | (1023 - row). Live <=> key >= 1024.
// Per round extract top-2 (a1, a2). a2 is the next greedy pick iff
// IoU(a1,a2) <= 0.5 (exact f64 check) — then both emit and suppression tests
// each box against both picks in one pass. Suppression RN(inter/denom)>0.5
// computed exactly in f64 (no division). Sticky streams: kc = -kept.
__global__ __launch_bounds__(256) void k_nms(const float* boxes, const float* sv,
                                             float* keptScore, int* keptRow, int* kc) {
  int bc = blockIdx.x;              // 0..639
  int b = bc / NCLS;
  int c = bc - b * NCLS;
  int tid = threadIdx.x;
  int wv = tid >> 6, lane = tid & 63;

  __shared__ float4 s_box[TOPK];            // 16 KB (offset coords)
  __shared__ float  s_ard[TOPK];            // 4 KB: |val| = area, sign = degenerate
  __shared__ unsigned long long s_p2[2][4]; // parity-buffered per-wave (top1,top2)

  float x1[4], y1[4], x2[4], y2[4], ar[4];
  unsigned key[4];
  float off = (float)c * CLS_OFF;   // exact in f32
  #pragma unroll
  for (int j = 0; j < 4; ++j) {
    int row = j * 256 + tid;
    if (row < TOPK) {
      float4 bo = ((const float4*)boxes)[b * TOPK + row];
      // reference computes IoU/areas on OFFSET coords (f32-rounded) — replicate
      float a = bo.x + off, d = bo.y + off, e = bo.z + off, f = bo.w + off;
      x1[j] = a; y1[j] = d; x2[j] = e; y2[j] = f;
      ar[j] = (e - a) * (f - d);
      unsigned bits = __float_as_uint(sv[((size_t)(b * TOPK + row)) * NCLS + c]);
      key[j] = ((bits & 0x3FFFFFu) << 10) | (1023u - (unsigned)row);
      // self-IoU = RN(ar / RN(ar+1e-6)); degenerate <=> !(selfiou > 0.5)
      float sden = ar[j] + 1e-6f;
      bool deg = !((double)ar[j] > (double)sden * K2_HALF_UP);
      float4 sb; sb.x = a; sb.y = d; sb.z = e; sb.w = f;
      s_box[row] = sb;
      s_ard[row] = __uint_as_float(__float_as_uint(ar[j]) | (deg ? 0x80000000u : 0u));
    } else {
      x1[j] = y1[j] = x2[j] = y2[j] = ar[j] = 0.0f;
      key[j] = 0u;
    }
  }
  __syncthreads();   // boxes visible

  int kept = 0;
  bool sticky = false;
  float* ks = keptScore + (size_t)(b * NCLS + c) * MAXPER;
  int*   kr = keptRow   + (size_t)(b * NCLS + c) * MAXPER;

  for (int round = 0; round < MAXPER; ++round) {
    int par = round & 1;
    // local top-2 of 4 keys (positions distinct; keys unique when live)
    unsigned hi1 = max(key[0], key[1]), lo1 = min(key[0], key[1]);
    unsigned hi2 = max(key[2], key[3]), lo2 = min(key[2], key[3]);
    unsigned m1 = max(hi1, hi2);
    unsigned m2 = max(min(hi1, hi2), max(lo1, lo2));
    unsigned w1, w2;
    wave_red_top2(m1, m2, w1, w2);
    if (lane == 0) s_p2[par][wv] = ((unsigned long long)w1 << 32) | w2;
    __syncthreads();                          // ONE barrier per round
    unsigned k0 = 0u, k1 = 0u;
    #pragma unroll
    for (int w = 0; w < 4; ++w) {
      unsigned long long pp = s_p2[par][w];
      unsigned p1 = (unsigned)(pp >> 32), p2 = (unsigned)pp;
      unsigned tm = min(k0, p1);
      k0 = max(k0, p1);
      k1 = max(tm, max(k1, p2));
    }
    if (k0 < 1024u) break;                    // no live entries
    // ---- pick a1 ----
    int brow1 = 1023 - (int)(k0 & 1023u);
    float bs1 = __uint_as_float(0x3F000000u | (k0 >> 10));
    float4 bb1 = s_box[brow1];
    unsigned au1 = __float_as_uint(s_ard[brow1]);
    bool deg1 = (au1 >> 31) != 0u;
    float ba1 = __uint_as_float(au1 & 0x7FFFFFFFu);
    if (tid == 0) { ks[kept] = bs1; kr[kept] = brow1; }
    kept++;
    if (deg1) { sticky = true; break; }       // repeats forever in the ref scan
    if (kept >= MAXPER) break;
    // ---- try pick a2 (pre-suppression 2nd max) ----
    bool do2 = false, deg2 = false;
    float4 bb2; float ba2 = 0.0f;
    if (k1 >= 1024u) {
      int brow2 = 1023 - (int)(k1 & 1023u);
      float bs2 = __uint_as_float(0x3F000000u | (k1 >> 10));
      bb2 = s_box[brow2];
      unsigned au2 = __float_as_uint(s_ard[brow2]);
      deg2 = (au2 >> 31) != 0u;
      ba2 = __uint_as_float(au2 & 0x7FFFFFFFu);
      // a2 is next pick iff not suppressed by a1 (exact ref arithmetic)
      float ltx = fmaxf(bb1.x, bb2.x), rbx = fminf(bb1.z, bb2.z);
      float lty = fmaxf(bb1.y, bb2.y), rby = fminf(bb1.w, bb2.w);
      float w_ = fmaxf(rbx - ltx, 0.0f), h_ = fmaxf(rby - lty, 0.0f);
      float inter = w_ * h_;
      float denom = ((ba1 + ba2) - inter) + 1e-6f;
      if (!((double)inter > (double)denom * K2_HALF_UP)) {
        do2 = true;
        if (tid == 0) { ks[kept] = bs2; kr[kept] = brow2; }
        kept++;
      }
    }
    if (do2 && deg2) { sticky = true; break; }
    // ---- suppression: each box vs a1 (and a2 if emitted); OR == sequential ----
    #pragma unroll
    for (int j = 0; j < 4; ++j) {
      {
        float ltx = fmaxf(bb1.x, x1[j]), rbx = fminf(bb1.z, x2[j]);
        float lty = fmaxf(bb1.y, y1[j]), rby = fminf(bb1.w, y2[j]);
        float w_ = fmaxf(rbx - ltx, 0.0f), h_ = fmaxf(rby - lty, 0.0f);
        float inter = w_ * h_;
        float denom = ((ba1 + ar[j]) - inter) + 1e-6f;
        if ((double)inter > (double)denom * K2_HALF_UP) key[j] = 0u;
      }
      if (do2) {
        float ltx = fmaxf(bb2.x, x1[j]), rbx = fminf(bb2.z, x2[j]);
        float lty = fmaxf(bb2.y, y1[j]), rby = fminf(bb2.w, y2[j]);
        float w_ = fmaxf(rbx - ltx, 0.0f), h_ = fmaxf(rby - lty, 0.0f);
        float inter = w_ * h_;
        float denom = ((ba2 + ar[j]) - inter) + 1e-6f;
        if ((double)inter > (double)denom * K2_HALF_UP) key[j] = 0u;
      }
    }
    if (kept >= MAXPER) break;
  }
  if (tid == 0) kc[b * NCLS + c] = sticky ? -kept : kept;
}

// ---------------- K5: sort-based merge -> top-100 ----------------
// Global sort of the stream union by (score desc, flat asc) == merge-by-max-head
// (streams are emitted in that order; sticky element repeats forever =>
// truncate at first sticky, pad with it to 100).
__global__ __launch_bounds__(256) void k_merge(const float* boxes, const float* keptScore,
                                               const int* keptRow, const int* kc, float* out) {
  int b = blockIdx.x;
  int tid = threadIdx.x;
  int wv = tid >> 6, lane = tid & 63;
  __shared__ int s_kc[NCLS];
  __shared__ int s_part[2][4];
  __shared__ int s_pos;
  __shared__ int s_sticky;
  __shared__ int s_navail;
  __shared__ unsigned long long s_pool[POOL];   // 2 KB

  for (int c = tid; c < NCLS; c += 256) s_kc[c] = kc[b * NCLS + c];
  if (tid == 0) { s_pos = 0; s_sticky = 0x7FFFFFFF; s_navail = 0; }
  for (int i = tid; i < POOL; i += 256) s_pool[i] = 0ull;
  __syncthreads();

  // load all stream scores into registers (coalesced; invalid -> 0)
  unsigned sc[32];
  #pragma unroll
  for (int s = 0; s < 32; ++s) {
    int i = tid + s * 256;
    unsigned vv = 0u;
    if (i < NCLS * MAXPER) {
      int c = i / MAXPER, k = i - c * MAXPER;
      int kcv = s_kc[c];
      int ka = (kcv < 0) ? -kcv : kcv;
      if (k < ka) vv = __float_as_uint(keptScore[(size_t)b * NCLS * MAXPER + i]);
    }
    sc[s] = vv;
  }

  int par = 0;
  auto countGE = [&](unsigned mid) -> int {
    int c = 0;
    #pragma unroll
    for (int s = 0; s < 32; ++s) c += (sc[s] >= mid) ? 1 : 0;
    c = wave_red_sum_i32(c);
    if (lane == 0) s_part[par][wv] = c;
    __syncthreads();
    int tot = s_part[par][0] + s_part[par][1] + s_part[par][2] + s_part[par][3];
    par ^= 1;
    return tot;
  };

  // all valid scores are sig(sig(x)) in (0.5, 0.734): bits in [0x3F000001, 0x3F3C0000)
  int T = countGE(0x3F000001u);        // total stream entries
  unsigned V = 0x3F000001u;            // pool threshold (all valid if T <= 100)
  if (T > MAXPER) {
    unsigned lo = 0x3F000001u, hi = 0x3F3C0000u;
    while (hi - lo > 1u) {
      unsigned mid = lo + (hi - lo) / 2u;
      if (countGE(mid) >= MAXPER) lo = mid; else hi = mid;
    }
    V = lo;   // count(>=V) >= 100, count(>V) < 100
  }

  // gather candidate pool (>= V). Overflow beyond POOL needs >=157 exact f32
  // score ties at the boundary — not reachable with continuous inputs.
  #pragma unroll
  for (int s = 0; s < 32; ++s) {
    if (sc[s] >= V) {
      int i = tid + s * 256;
      int c = i / MAXPER, k = i - c * MAXPER;
      int kcv = s_kc[c];
      int ka = (kcv < 0) ? -kcv : kcv;
      unsigned st = (kcv < 0 && k == ka - 1) ? 1u : 0u;
      unsigned row = (unsigned)keptRow[(size_t)b * NCLS * MAXPER + i];
      unsigned flat = row * 80u + (unsigned)c;
      int p = atomicAdd(&s_pos, 1);
      if (p < POOL)
        s_pool[p] = ((unsigned long long)sc[s] << 32) |
                    (unsigned long long)(0x7FFFFFFFu - ((flat << 1) | st));
    }
  }
  __syncthreads();

  // bitonic sort POOL u64 keys, descending (zeros sink to the end)
  for (unsigned k = 2; k <= POOL; k <<= 1) {
    for (unsigned j = k >> 1; j > 0; j >>= 1) {
      if (tid < POOL) {
        unsigned i = (unsigned)tid, l = i ^ j;
        if (l > i) {
          unsigned long long a = s_pool[i], bk = s_pool[l];
          bool sw = ((i & k) == 0) ? (a < bk) : (a > bk);
          if (sw) { s_pool[i] = bk; s_pool[l] = a; }
        }
      }
      __syncthreads();
    }
  }

  // first sticky position among the leading valid entries; valid count
  if (tid < MAXPER) {
    unsigned long long key = s_pool[tid];
    if (key != 0ull) {
      atomicAdd(&s_navail, 1);
      if ((((unsigned)key) & 1u) == 0u) atomicMin(&s_sticky, tid);  // low bit 0 <=> sticky
    }
  }
  __syncthreads();
  int navail = s_navail;               // valid entries form a prefix after sort
  int p = s_sticky;
  int n = (p < navail) ? MAXPER : navail;

  // output layout (flat f32): [B] ndet | [B,100,4] boxes | [B,100] scores | [B,100] cls
  if (tid == 0) out[b] = (float)n;
  const int OB = BATCH;                    // 8
  const int OP = OB + BATCH * MAXPER * 4;  // 3208
  const int OS = OP + BATCH * MAXPER;      // 4008
  if (tid < MAXPER) {
    int k = tid;
    float bx0 = 0.f, bx1 = 0.f, bx2 = 0.f, bx3 = 0.f, scf = 0.f, cf = -1.0f;
    if (k < n) {
      int idx = (k > p) ? p : k;           // p == INT_MAX when no sticky -> idx = k
      unsigned long long key = s_pool[idx];
      unsigned flat = (0x7FFFFFFFu - (unsigned)key) >> 1;
      unsigned cls = flat % 80u;
      unsigned row = flat / 80u;
      float4 bo = ((const float4*)boxes)[b * TOPK + row];
      bx0 = bo.x; bx1 = bo.y; bx2 = bo.z; bx3 = bo.w;
      scf = __uint_as_float((unsigned)(key >> 32));
      cf = (float)cls;
    }
    float* po = out + OB + (size_t)(b * MAXPER + k) * 4;
    po[0] = bx0; po[1] = bx1; po[2] = bx2; po[3] = bx3;
    out[OP + b * MAXPER + k] = scf;
    out[OS + b * MAXPER + k] = cf;
  }
}

extern "C" void kernel_launch(void* const* d_in, const int* in_sizes, int n_in,
                              void* d_out, int out_size, void* d_ws, size_t ws_size,
                              hipStream_t stream) {
  InPtrs P;
  for (int l = 0; l < 5; ++l) {
    P.cls[l]  = (const float*)d_in[4 * l + 0];
    P.bbox[l] = (const float*)d_in[4 * l + 1];
    P.shp[l]  = (const float*)d_in[4 * l + 2];
    P.loc[l]  = (const float*)d_in[4 * l + 3];
  }
  float* maxscore  = (float*)d_ws;                          // B*NA
  int*   sel       = (int*)(maxscore + BATCH * NA);         // B*TOPK
  float* boxes     = (float*)(sel + BATCH * TOPK);          // B*TOPK*4 (16B aligned)
  float* sv        = boxes + BATCH * TOPK * 4;              // B*TOPK*80 (row-major)
  float* keptScore = sv + BATCH * TOPK * NCLS;              // B*80*100
  int*   keptRow   = (int*)(keptScore + BATCH * NCLS * MAXPER);
  int*   kc        = keptRow + BATCH * NCLS * MAXPER;
  float* out = (float*)d_out;

  k_maxscore<<<(BATCH * (NA / 4) + 255) / 256, 256, 0, stream>>>(P, maxscore);
  k_select<<<BATCH, 1024, 0, stream>>>(maxscore, sel);
  k_gather<<<(BATCH * TOPK + 3) / 4, 256, 0, stream>>>(P, sel, boxes, sv);
  k_nms<<<BATCH * NCLS, 256, 0, stream>>>(boxes, sv, keptScore, keptRow, kc);
  k_merge<<<BATCH, 256, 0, stream>>>(boxes, keptScore, keptRow, kc, out);
}